// Round 7
// baseline (326.295 us; speedup 1.0000x reference)
//
#include <hip/hip_runtime.h>
#include <hip/hip_bf16.h>

// LuongAttention: B=16, Tq=512, Tk=2048, D=1024 (fp32 in/out)
// Fast path (ws >= 224 MiB):
//   P0: split_enc_T: enc -> enc_h/enc_l + encT (fused transpose); dec/W splits
//   K1: dproj_h/l = split(dec @ W^T)   gemm_wide<1,1,4>  (128x256, 2-ph dbuf)
//   K2: score = dproj @ enc^T          gemm_wide<1,0,8>  (256x256, 2-ph dbuf)
//   K3: softmax in place + bf16 copy (align_b)
//   K4: ctx = align_b @ encT^T         gemm_wide<0,0,4>  (128x256, 2-ph dbuf)
// GEMMs use mfma_f32_32x32x16_bf16 (2495 TF pipe vs 2176 for 16x16; half the
// instruction count -> more issue slots for ds_read/staging overlap).
// 2-phase schedule (round-4 proven): stage(next buf) issued BEFORE compute(cur),
// one __syncthreads per K-tile. Phase-split w/ drain-0 was tried and hurt
// (m218: drain-0 8-phase == 1-phase; counted-vmcnt needs 3 buffers > LDS).
// Mid path (160..224 MiB): encT aliases enc_l -> separate transpose after K2.
// Fallback (<160 MiB): round-1 kernels. wa_bias cancels in softmax -> skipped.

typedef float f32x4 __attribute__((ext_vector_type(4)));
typedef float f32x16 __attribute__((ext_vector_type(16)));
typedef __bf16 bf16x8 __attribute__((ext_vector_type(8)));
typedef unsigned short u16x4 __attribute__((ext_vector_type(4)));
typedef unsigned short u16x8 __attribute__((ext_vector_type(8)));

__device__ inline unsigned short f2bf(float f) {
    union { float f; unsigned int u; } v; v.f = f;
    unsigned int r = v.u + 0x7fffu + ((v.u >> 16) & 1u);  // RN-even
    return (unsigned short)(r >> 16);
}
__device__ inline float bf2f(unsigned short h) {
    union { unsigned int u; float f; } v; v.u = ((unsigned int)h) << 16; return v.f;
}

__device__ inline void gload16(const void* g, const void* l) {
    __builtin_amdgcn_global_load_lds(
        (const __attribute__((address_space(1))) unsigned int*)g,
        (__attribute__((address_space(3))) unsigned int*)l, 16, 0, 0);
}

// ---------------- P0: fp32 -> bf16 hi/lo split (elementwise) ----------------
__global__ __launch_bounds__(256)
void split_bf16(const float* __restrict__ x, unsigned short* __restrict__ ho,
                unsigned short* __restrict__ lo, int n8)
{
    int i = blockIdx.x * 256 + threadIdx.x;
    if (i >= n8) return;
    const f32x4* xp = reinterpret_cast<const f32x4*>(x + (size_t)i * 8);
    f32x4 v0 = xp[0], v1 = xp[1];
    u16x8 h, l;
#pragma unroll
    for (int j = 0; j < 4; ++j) {
        unsigned short hh = f2bf(v0[j]);
        h[j] = hh; l[j] = f2bf(v0[j] - bf2f(hh));
        hh = f2bf(v1[j]);
        h[4 + j] = hh; l[4 + j] = f2bf(v1[j] - bf2f(hh));
    }
    *reinterpret_cast<u16x8*>(ho + (size_t)i * 8) = h;
    *reinterpret_cast<u16x8*>(lo + (size_t)i * 8) = l;
}

// ---- P0 fused: enc fp32 -> enc_h, enc_l (row-major) + encT (hi transposed) -
__global__ __launch_bounds__(256)
void split_enc_T(const float* __restrict__ enc, unsigned short* __restrict__ eh,
                 unsigned short* __restrict__ el, unsigned short* __restrict__ eT)
{
    __shared__ unsigned short t[64][72];
    const int b = blockIdx.z;
    const int kb = blockIdx.x * 64;   // Tk
    const int db = blockIdx.y * 64;   // D
    const int r = threadIdx.x >> 4;          // 0..15
    const int c0 = (threadIdx.x & 15) * 4;   // 0..60
    const float* ip = enc + ((size_t)b * 2048 + kb) * 1024 + db;
#pragma unroll
    for (int it = 0; it < 4; ++it) {
        int row = it * 16 + r;
        f32x4 v = *reinterpret_cast<const f32x4*>(ip + (size_t)row * 1024 + c0);
        u16x4 h, l;
#pragma unroll
        for (int j = 0; j < 4; ++j) {
            h[j] = f2bf(v[j]); l[j] = f2bf(v[j] - bf2f(h[j]));
        }
        size_t go = ((size_t)b * 2048 + kb + row) * 1024 + db + c0;
        *reinterpret_cast<u16x4*>(eh + go) = h;
        *reinterpret_cast<u16x4*>(el + go) = l;
#pragma unroll
        for (int j = 0; j < 4; ++j) t[c0 + j][row] = h[j];
    }
    __syncthreads();
    const int d = threadIdx.x >> 2;   // 0..63
    const int ch = threadIdx.x & 3;   // k-chunk of 16
    unsigned short* op = eT + ((size_t)b * 1024 + db + d) * 2048 + kb + ch * 16;
    u16x8 w0, w1;
#pragma unroll
    for (int j = 0; j < 8; ++j) { w0[j] = t[d][ch * 16 + j]; w1[j] = t[d][ch * 16 + 8 + j]; }
    *reinterpret_cast<u16x8*>(op) = w0;
    *reinterpret_cast<u16x8*>(op + 8) = w1;
}

// ------- T: bf16 transpose (mid-path only) ----------------------------------
__global__ __launch_bounds__(256)
void transpose_bf16(const unsigned short* __restrict__ in, unsigned short* __restrict__ out)
{
    __shared__ unsigned short t[64][65];
    const int b = blockIdx.z;
    const int kb = blockIdx.x * 64;
    const int db = blockIdx.y * 64;
    const unsigned short* ip = in + ((size_t)b * 2048 + kb) * 1024 + db;
    unsigned short* op = out + ((size_t)b * 1024 + db) * 2048 + kb;
    const int r = threadIdx.x >> 3;
    const int c0 = (threadIdx.x & 7) * 8;
#pragma unroll
    for (int h = 0; h < 2; ++h) {
        u16x8 v = *reinterpret_cast<const u16x8*>(ip + (size_t)(r + h * 32) * 1024 + c0);
#pragma unroll
        for (int j = 0; j < 8; ++j) t[c0 + j][r + h * 32] = v[j];
    }
    __syncthreads();
#pragma unroll
    for (int h = 0; h < 2; ++h) {
        int orow = r + h * 32;
        u16x8 v = *reinterpret_cast<const u16x8*>(&t[orow][c0]);
        *reinterpret_cast<u16x8*>(op + (size_t)orow * 2048 + c0) = v;
    }
}

// ========== generalized wide BT GEMM, 32x32x16 MFMA, 2-phase dbuf ===========
// C = A @ B^T (X3: (Ah+Al)@(Bh+Bl)^T, hi*hi+hi*lo+lo*hi). A [M,K], B [N,K]
// bf16 planes, K%32==0. BM=32*AM, BN=256, BK=32, 8 waves (2x4), wave-tile
// (16*AM)x64 built from 32x32 blocks: MB=AM/2 row-blocks x 2 col-blocks x
// 2 k-halves. acc[MB][2] f32x16. LDS rows 64B, phys chunk=(kc+(row>>1))&3
// (8 consecutive lanes cover all 32 banks -> conflict-free). Linear LDS dest
// (gload_lds) + pre-swizzled global src. 2-phase: stage(next) issued before
// compute(cur), one __syncthreads per K-tile. Grid: 1D nwg (nwg%8==0),
// XCD-swizzled. OUTMODE 0: fp32 C. OUTMODE 1: bf16 hi/lo split -> Ch, Cl.
// A/B frag (32x32x16): lane reads row/col = base + (lane&31),
// k = h*16 + (lane>>5)*8 + j  (A,B share the mapping -> permutation-safe).
// C/D layout [HW-verified m74/m101]: col=lane&31, row=(r&3)+8*(r>>2)+4*(lane>>5).
template<int X3, int OUTMODE, int AM>
__global__ __launch_bounds__(512, 2)
void gemm_wide(const unsigned short* __restrict__ Ah, const unsigned short* __restrict__ Al,
               long long sA,
               const unsigned short* __restrict__ Bh, const unsigned short* __restrict__ Bl,
               long long sB,
               float* __restrict__ C, unsigned short* __restrict__ Ch,
               unsigned short* __restrict__ Cl, long long sC,
               int M, int N, int K)
{
    constexpr int BM  = 32 * AM;
    constexpr int MB  = AM / 2;                   // 32-row blocks per wave
    constexpr int LVL = (BM + 256) * 32;          // u16 elems per plane level
    constexpr int BUF = LVL * (X3 ? 2 : 1);
    constexpr int NI  = (BM + 256) / 128;         // gload16 per thread per plane
    __shared__ unsigned short smem[2 * BUF];

    const int tid = threadIdx.x, lane = tid & 63, wave = tid >> 6;

    // XCD swizzle + batch decode (m-fastest)
    const int nwg = gridDim.x;
    int orig = (blockIdx.x & 7) * (nwg >> 3) + (blockIdx.x >> 3);
    const int mb = M / BM, nb = N >> 8, bpb = mb * nb;
    const int z = orig / bpb, rem = orig - z * bpb;
    const int bm = (rem % mb) * BM, bn = (rem / mb) << 8;

    Ah += (size_t)z * sA; Bh += (size_t)z * sB;
    if (X3) { Al += (size_t)z * sA; Bl += (size_t)z * sB; }

    // staging geometry: slot c = i*512+tid -> row=c>>2, phys slot s=c&3 holds
    // global chunk g = (s - (r>>1)) & 3 (r = per-matrix row).
    const unsigned short* srcH[NI];
    const unsigned short* srcL[NI];
    int dst[NI];
#pragma unroll
    for (int i = 0; i < NI; ++i) {
        int c = i * 512 + tid, row = c >> 2, s = c & 3;
        int isA = row < BM;
        int r = isA ? row : row - BM;
        int g = (s + 4 - ((r >> 1) & 3)) & 3;
        srcH[i] = (isA ? Ah + (size_t)(bm + r) * K : Bh + (size_t)(bn + r) * K) + g * 8;
        if (X3) srcL[i] = (isA ? Al + (size_t)(bm + r) * K : Bl + (size_t)(bn + r) * K) + g * 8;
        dst[i] = row * 32 + s * 8;
    }

    const int l31 = lane & 31, lh = lane >> 5;    // frag row offset, k-half-half
    const int wrow = (wave >> 2) * (16 * AM);
    const int wcol = (wave & 3) * 64;

    f32x16 acc[MB][2] = {};
    const int nt = K >> 5;
    int cur = 0;

    {   // prologue: stage K-tile 0 into buf 0
#pragma unroll
        for (int i = 0; i < NI; ++i) {
            gload16(srcH[i], smem + dst[i]);
            if constexpr (X3) gload16(srcL[i], smem + LVL + dst[i]);
        }
    }
    __syncthreads();

    for (int t = 0; t < nt; ++t) {
        if (t + 1 < nt) {   // issue next-tile stage BEFORE compute (2-phase)
            const int kt = (t + 1) << 5;
            unsigned short* bx = smem + (cur ^ 1) * BUF;
#pragma unroll
            for (int i = 0; i < NI; ++i) {
                gload16(srcH[i] + kt, bx + dst[i]);
                if constexpr (X3) gload16(srcL[i] + kt, bx + LVL + dst[i]);
            }
        }
        const unsigned short* base = smem + cur * BUF;
        // B fragments: 2 col-blocks x 2 k-halves (held in reg)
        bf16x8 bh[2][2], bl[2][2];
#pragma unroll
        for (int n = 0; n < 2; ++n)
#pragma unroll
            for (int h = 0; h < 2; ++h) {
                int rB = wcol + n * 32 + l31;
                int off = (BM + rB) * 32 + (((h * 2 + lh + (rB >> 1)) & 3) << 3);
                bh[n][h] = *reinterpret_cast<const bf16x8*>(base + off);
                if constexpr (X3) bl[n][h] = *reinterpret_cast<const bf16x8*>(base + LVL + off);
            }
#pragma unroll
        for (int m = 0; m < MB; ++m) {
            bf16x8 ah[2], al[2];
#pragma unroll
            for (int h = 0; h < 2; ++h) {
                int rA = wrow + m * 32 + l31;
                int off = rA * 32 + (((h * 2 + lh + (rA >> 1)) & 3) << 3);
                ah[h] = *reinterpret_cast<const bf16x8*>(base + off);
                if constexpr (X3) al[h] = *reinterpret_cast<const bf16x8*>(base + LVL + off);
            }
#pragma unroll
            for (int n = 0; n < 2; ++n)
#pragma unroll
                for (int h = 0; h < 2; ++h) {
                    acc[m][n] = __builtin_amdgcn_mfma_f32_32x32x16_bf16(ah[h], bh[n][h], acc[m][n], 0, 0, 0);
                    if constexpr (X3) {
                        acc[m][n] = __builtin_amdgcn_mfma_f32_32x32x16_bf16(ah[h], bl[n][h], acc[m][n], 0, 0, 0);
                        acc[m][n] = __builtin_amdgcn_mfma_f32_32x32x16_bf16(al[h], bh[n][h], acc[m][n], 0, 0, 0);
                    }
                }
        }
        __syncthreads();   // drains vmcnt: next buf staged; reads of cur done
        cur ^= 1;
    }

    // C/D layout (32x32): col = lane&31, row = (r&3) + 8*(r>>2) + 4*(lane>>5)
    if constexpr (OUTMODE == 0) {
        float* Cz = C + (size_t)z * sC;
#pragma unroll
        for (int m = 0; m < MB; ++m)
#pragma unroll
            for (int r = 0; r < 16; ++r) {
                int grow = bm + wrow + m * 32 + (r & 3) + 8 * (r >> 2) + 4 * lh;
                float* cr = Cz + (size_t)grow * N + bn + wcol + l31;
#pragma unroll
                for (int n = 0; n < 2; ++n) cr[n * 32] = acc[m][n][r];
            }
    } else {
        unsigned short* Chz = Ch + (size_t)z * sC;
        unsigned short* Clz = Cl + (size_t)z * sC;
#pragma unroll
        for (int m = 0; m < MB; ++m)
#pragma unroll
            for (int r = 0; r < 16; ++r) {
                int grow = bm + wrow + m * 32 + (r & 3) + 8 * (r >> 2) + 4 * lh;
                size_t rb = (size_t)grow * N + bn + wcol + l31;
#pragma unroll
                for (int n = 0; n < 2; ++n) {
                    float v = acc[m][n][r];
                    unsigned short hh = f2bf(v);
                    Chz[rb + n * 32] = hh;
                    Clz[rb + n * 32] = f2bf(v - bf2f(hh));
                }
            }
    }
}

// ---------------- softmax rows (2048 cols) + optional bf16 copy -------------
__global__ __launch_bounds__(256)
void softmax_rows(float* __restrict__ P, unsigned short* __restrict__ albf)
{
    __shared__ float redm[4], reds[4];
    float* p = P + (size_t)blockIdx.x * 2048;
    const int tid = threadIdx.x, lane = tid & 63, wave = tid >> 6;

    f32x4 v0 = *reinterpret_cast<const f32x4*>(p + tid * 4);
    f32x4 v1 = *reinterpret_cast<const f32x4*>(p + 1024 + tid * 4);

    float mx = fmaxf(fmaxf(fmaxf(v0[0], v0[1]), fmaxf(v0[2], v0[3])),
                     fmaxf(fmaxf(v1[0], v1[1]), fmaxf(v1[2], v1[3])));
#pragma unroll
    for (int o = 32; o; o >>= 1) mx = fmaxf(mx, __shfl_xor(mx, o));
    if (lane == 0) redm[wave] = mx;
    __syncthreads();
    mx = fmaxf(fmaxf(redm[0], redm[1]), fmaxf(redm[2], redm[3]));

    float s = 0.f;
#pragma unroll
    for (int j = 0; j < 4; ++j) { v0[j] = __expf(v0[j] - mx); s += v0[j]; }
#pragma unroll
    for (int j = 0; j < 4; ++j) { v1[j] = __expf(v1[j] - mx); s += v1[j]; }
#pragma unroll
    for (int o = 32; o; o >>= 1) s += __shfl_xor(s, o);
    if (lane == 0) reds[wave] = s;
    __syncthreads();
    s = reds[0] + reds[1] + reds[2] + reds[3];

    const float inv = 1.0f / s;
#pragma unroll
    for (int j = 0; j < 4; ++j) { v0[j] *= inv; v1[j] *= inv; }
    *reinterpret_cast<f32x4*>(p + tid * 4) = v0;
    *reinterpret_cast<f32x4*>(p + 1024 + tid * 4) = v1;

    if (albf) {
        unsigned short* ab = albf + (size_t)blockIdx.x * 2048;
        u16x4 h0, h1;
#pragma unroll
        for (int j = 0; j < 4; ++j) { h0[j] = f2bf(v0[j]); h1[j] = f2bf(v1[j]); }
        *reinterpret_cast<u16x4*>(ab + tid * 4) = h0;
        *reinterpret_cast<u16x4*>(ab + 1024 + tid * 4) = h1;
    }
}

// ======================= round-1 fallback kernels ===========================
__device__ inline int tile_byte(int row, int kElem) {
    int chunk = kElem >> 3;
    return row * 128 + ((chunk ^ (row & 7)) << 4) + ((kElem & 7) << 1);
}

__global__ __launch_bounds__(256, 2)
void gemm_bt_x3(const float* __restrict__ A, long long sA,
                const float* __restrict__ Bt, long long sB,
                float* __restrict__ C, long long sC,
                int M, int N, int K)
{
    __shared__ unsigned short Ah[128 * 64], Al[128 * 64];
    __shared__ unsigned short Bh[128 * 64], Bl[128 * 64];

    const int tid = threadIdx.x, lane = tid & 63, wave = tid >> 6;
    const int wr = (wave >> 1) * 64, wc = (wave & 1) * 64;
    const int bm = blockIdx.y * 128, bn = blockIdx.x * 128;
    A += (size_t)blockIdx.z * sA;
    Bt += (size_t)blockIdx.z * sB;
    C += (size_t)blockIdx.z * sC;

    f32x4 acc[4][4] = {};

    for (int kt = 0; kt < K; kt += 64) {
#pragma unroll
        for (int i = 0; i < 8; ++i) {
            int idx = tid + i * 256;
            int row = idx >> 4, f4 = idx & 15;
            f32x4 va = *reinterpret_cast<const f32x4*>(A + (size_t)(bm + row) * K + kt + f4 * 4);
            f32x4 vb = *reinterpret_cast<const f32x4*>(Bt + (size_t)(bn + row) * K + kt + f4 * 4);
            u16x4 ah, al, bh, bl;
#pragma unroll
            for (int j = 0; j < 4; ++j) {
                unsigned short h = f2bf(va[j]);
                ah[j] = h; al[j] = f2bf(va[j] - bf2f(h));
                h = f2bf(vb[j]);
                bh[j] = h; bl[j] = f2bf(vb[j] - bf2f(h));
            }
            int off = tile_byte(row, f4 * 4);
            *reinterpret_cast<u16x4*>((char*)Ah + off) = ah;
            *reinterpret_cast<u16x4*>((char*)Al + off) = al;
            *reinterpret_cast<u16x4*>((char*)Bh + off) = bh;
            *reinterpret_cast<u16x4*>((char*)Bl + off) = bl;
        }
        __syncthreads();
#pragma unroll
        for (int kk = 0; kk < 2; ++kk) {
            bf16x8 a_h[4], a_l[4], b_h[4], b_l[4];
            const int kbase = kk * 32 + (lane >> 4) * 8;
#pragma unroll
            for (int m = 0; m < 4; ++m) {
                int off = tile_byte(wr + m * 16 + (lane & 15), kbase);
                a_h[m] = *reinterpret_cast<const bf16x8*>((char*)Ah + off);
                a_l[m] = *reinterpret_cast<const bf16x8*>((char*)Al + off);
            }
#pragma unroll
            for (int n = 0; n < 4; ++n) {
                int off = tile_byte(wc + n * 16 + (lane & 15), kbase);
                b_h[n] = *reinterpret_cast<const bf16x8*>((char*)Bh + off);
                b_l[n] = *reinterpret_cast<const bf16x8*>((char*)Bl + off);
            }
#pragma unroll
            for (int m = 0; m < 4; ++m)
#pragma unroll
                for (int n = 0; n < 4; ++n) {
                    acc[m][n] = __builtin_amdgcn_mfma_f32_16x16x32_bf16(a_h[m], b_h[n], acc[m][n], 0, 0, 0);
                    acc[m][n] = __builtin_amdgcn_mfma_f32_16x16x32_bf16(a_h[m], b_l[n], acc[m][n], 0, 0, 0);
                    acc[m][n] = __builtin_amdgcn_mfma_f32_16x16x32_bf16(a_l[m], b_h[n], acc[m][n], 0, 0, 0);
                }
        }
        __syncthreads();
    }
#pragma unroll
    for (int m = 0; m < 4; ++m)
#pragma unroll
        for (int j = 0; j < 4; ++j) {
            int grow = bm + wr + m * 16 + (lane >> 4) * 4 + j;
            float* cr = C + (size_t)grow * N + bn + wc + (lane & 15);
#pragma unroll
            for (int n = 0; n < 4; ++n) cr[n * 16] = acc[m][n][j];
        }
}

__global__ __launch_bounds__(256, 2)
void gemm_nn_bf16(const float* __restrict__ A, long long sA,
                  const float* __restrict__ Bn, long long sB,
                  float* __restrict__ C, long long sC,
                  int M, int N, int K)
{
    __shared__ unsigned short As[128 * 64];
    __shared__ unsigned short Bs[64 * 130];

    const int tid = threadIdx.x, lane = tid & 63, wave = tid >> 6;
    const int wr = (wave >> 1) * 64, wc = (wave & 1) * 64;
    const int bm = blockIdx.y * 128, bn = blockIdx.x * 128;
    A += (size_t)blockIdx.z * sA;
    Bn += (size_t)blockIdx.z * sB;
    C += (size_t)blockIdx.z * sC;

    f32x4 acc[4][4] = {};

    for (int kt = 0; kt < K; kt += 64) {
#pragma unroll
        for (int i = 0; i < 8; ++i) {
            int idx = tid + i * 256;
            int row = idx >> 4, f4 = idx & 15;
            f32x4 va = *reinterpret_cast<const f32x4*>(A + (size_t)(bm + row) * K + kt + f4 * 4);
            u16x4 h;
#pragma unroll
            for (int j = 0; j < 4; ++j) h[j] = f2bf(va[j]);
            *reinterpret_cast<u16x4*>((char*)As + tile_byte(row, f4 * 4)) = h;
        }
#pragma unroll
        for (int i = 0; i < 8; ++i) {
            int idx = tid + i * 256;
            int krow = idx >> 5, f4 = idx & 31;
            f32x4 vb = *reinterpret_cast<const f32x4*>(Bn + (size_t)(kt + krow) * N + bn + f4 * 4);
            unsigned int p0 = (unsigned int)f2bf(vb[0]) | ((unsigned int)f2bf(vb[1]) << 16);
            unsigned int p1 = (unsigned int)f2bf(vb[2]) | ((unsigned int)f2bf(vb[3]) << 16);
            unsigned int* bp = reinterpret_cast<unsigned int*>(&Bs[krow * 130 + f4 * 4]);
            bp[0] = p0; bp[1] = p1;
        }
        __syncthreads();
#pragma unroll
        for (int kk = 0; kk < 2; ++kk) {
            bf16x8 a[4], b[4];
            const int kbase = kk * 32 + (lane >> 4) * 8;
#pragma unroll
            for (int m = 0; m < 4; ++m)
                a[m] = *reinterpret_cast<const bf16x8*>((char*)As + tile_byte(wr + m * 16 + (lane & 15), kbase));
#pragma unroll
            for (int n = 0; n < 4; ++n) {
                int col = wc + n * 16 + (lane & 15);
                union { unsigned short u[8]; bf16x8 v; } t;
#pragma unroll
                for (int j = 0; j < 8; ++j) t.u[j] = Bs[(kbase + j) * 130 + col];
                b[n] = t.v;
            }
#pragma unroll
            for (int m = 0; m < 4; ++m)
#pragma unroll
                for (int n = 0; n < 4; ++n)
                    acc[m][n] = __builtin_amdgcn_mfma_f32_16x16x32_bf16(a[m], b[n], acc[m][n], 0, 0, 0);
        }
        __syncthreads();
    }
#pragma unroll
    for (int m = 0; m < 4; ++m)
#pragma unroll
        for (int j = 0; j < 4; ++j) {
            int grow = bm + wr + m * 16 + (lane >> 4) * 4 + j;
            float* cr = C + (size_t)grow * N + bn + wc + (lane & 15);
#pragma unroll
            for (int n = 0; n < 4; ++n) cr[n * 16] = acc[m][n][j];
        }
}

// ============================================================================
extern "C" void kernel_launch(void* const* d_in, const int* in_sizes, int n_in,
                              void* d_out, int out_size, void* d_ws, size_t ws_size,
                              hipStream_t stream)
{
    (void)in_sizes; (void)n_in; (void)out_size;
    const float* dec = (const float*)d_in[0];   // [16,512,1024]
    const float* enc = (const float*)d_in[1];   // [16,2048,1024]
    const float* W   = (const float*)d_in[2];   // [1024,1024]

    float* ctx   = (float*)d_out;                            // [16,512,1024]
    float* align = (float*)d_out + (size_t)16 * 512 * 1024;  // [16,512,2048]

    const size_t MiB = 1048576ULL;
    const size_t NEED_FUSED = 224 * MiB;
    const size_t NEED_FAST  = 160 * MiB;

    if (ws_size >= NEED_FAST) {
        const bool fused = (ws_size >= NEED_FUSED);
        unsigned short* enc_h   = (unsigned short*)d_ws;             // 64 MiB
        unsigned short* enc_l   = enc_h + 33554432ULL;               // 64 MiB
        unsigned short* encT    = fused ? (enc_l + 33554432ULL)
                                        : enc_l;                     // alias after K2
        unsigned short* align_b = fused ? (encT + 33554432ULL)
                                        : (enc_l + 33554432ULL);     // 32 MiB
        unsigned short* dproj_h = (unsigned short*)d_out;            // ctx region (dead)
        unsigned short* dproj_l = dproj_h + 8388608ULL;
        unsigned short* dec_h   = (unsigned short*)align;            // align region (dead)
        unsigned short* dec_l   = dec_h + 8388608ULL;
        unsigned short* W_h     = dec_l + 8388608ULL;
        unsigned short* W_l     = W_h + 1048576ULL;

        // P0: splits (+ fused transpose when encT has its own region)
        if (fused)
            split_enc_T<<<dim3(32, 16, 16), 256, 0, stream>>>(enc, enc_h, enc_l, encT);
        else
            split_bf16<<<16384, 256, 0, stream>>>(enc, enc_h, enc_l, 4194304);
        split_bf16<<<4096, 256, 0, stream>>>(dec, dec_h, dec_l, 1048576);
        split_bf16<<<512, 256, 0, stream>>>(W, W_h, W_l, 131072);

        // K1: dproj = dec @ W^T  (M=8192, N=1024, K=1024), 128x256
        gemm_wide<1, 1, 4><<<256, 512, 0, stream>>>(
            dec_h, dec_l, 0, W_h, W_l, 0,
            nullptr, dproj_h, dproj_l, 0, 8192, 1024, 1024);

        // K2: score = dproj @ enc^T per batch (M=512, N=2048, K=1024), 256x256
        gemm_wide<1, 0, 8><<<256, 512, 0, stream>>>(
            dproj_h, dproj_l, 512LL * 1024, enc_h, enc_l, 2048LL * 1024,
            align, nullptr, nullptr, 512LL * 2048, 512, 2048, 1024);

        // mid path: transpose enc_h into enc_l region (dead after K2)
        if (!fused)
            transpose_bf16<<<dim3(32, 16, 16), 256, 0, stream>>>(enc_h, encT);

        // K3: softmax + bf16 copy
        softmax_rows<<<8192, 256, 0, stream>>>(align, align_b);

        // K4: ctx = align_b @ encT^T per batch (M=512, N=1024, K=2048), 128x256
        gemm_wide<0, 0, 4><<<256, 512, 0, stream>>>(
            align_b, nullptr, 512LL * 2048, encT, nullptr, 1024LL * 2048,
            ctx, nullptr, nullptr, 512LL * 1024, 512, 1024, 2048);
    } else {
        // round-1 fallback (needs 32 MiB ws)
        float* dproj = (float*)d_ws;
        gemm_bt_x3<<<dim3(8, 64, 1), 256, 0, stream>>>(
            dec, 0, W, 0, dproj, 0, 8192, 1024, 1024);
        gemm_bt_x3<<<dim3(16, 4, 16), 256, 0, stream>>>(
            dproj, 512LL * 1024, enc, 2048LL * 1024, align, 512LL * 2048, 512, 2048, 1024);
        softmax_rows<<<8192, 256, 0, stream>>>(align, nullptr);
        gemm_nn_bf16<<<dim3(8, 4, 16), 256, 0, stream>>>(
            align, 512LL * 2048, enc, 2048LL * 1024, ctx, 512LL * 1024, 512, 1024, 2048);
    }
}

// Round 8
// 314.544 us; speedup vs baseline: 1.0374x; 1.0374x over previous
//
#include <hip/hip_runtime.h>
#include <hip/hip_bf16.h>

// LuongAttention: B=16, Tq=512, Tk=2048, D=1024 (fp32 in/out)
// Fast path (ws >= 224 MiB):
//   P0: split_enc_T: enc -> enc_h/enc_l + encT (fused transpose); dec/W splits
//   K1: dproj_h/l = split(dec @ W^T)   gemm_wide<1,1,4>  (128x256, 3-buf counted)
//   K2: score = dproj @ enc^T          gemm_wide<1,0,4>  (128x256, 3-buf counted)
//   K3: softmax in place + bf16 copy (align_b)
//   K4: ctx = align_b @ encT^T         gemm_wide<0,0,4>  (128x256, 3-buf counted)
// 16x16x32 MFMA (round-5 proven conflict-free frag layout; 32x32 regressed:
// 4-way LDS conflict, r7). 3-buffer pipeline with COUNTED vmcnt (T4, m218):
// per K-tile issue stage(t+2), compute t, s_waitcnt vmcnt(LPT) (t+2's loads
// stay in flight across the barrier - never drain to 0), raw s_barrier.
// Overwrite-safety: buf[(t+2)%3]'s previous reads retired before prior barrier.
// Mid path (160..224 MiB): encT aliases enc_l -> separate transpose after K2.
// Fallback (<160 MiB): round-1 kernels. wa_bias cancels in softmax -> skipped.

typedef float f32x4 __attribute__((ext_vector_type(4)));
typedef __bf16 bf16x8 __attribute__((ext_vector_type(8)));
typedef unsigned short u16x4 __attribute__((ext_vector_type(4)));
typedef unsigned short u16x8 __attribute__((ext_vector_type(8)));

__device__ inline unsigned short f2bf(float f) {
    union { float f; unsigned int u; } v; v.f = f;
    unsigned int r = v.u + 0x7fffu + ((v.u >> 16) & 1u);  // RN-even
    return (unsigned short)(r >> 16);
}
__device__ inline float bf2f(unsigned short h) {
    union { unsigned int u; float f; } v; v.u = ((unsigned int)h) << 16; return v.f;
}

__device__ inline void gload16(const void* g, const void* l) {
    __builtin_amdgcn_global_load_lds(
        (const __attribute__((address_space(1))) unsigned int*)g,
        (__attribute__((address_space(3))) unsigned int*)l, 16, 0, 0);
}

// ---------------- P0: fp32 -> bf16 hi/lo split (elementwise) ----------------
__global__ __launch_bounds__(256)
void split_bf16(const float* __restrict__ x, unsigned short* __restrict__ ho,
                unsigned short* __restrict__ lo, int n8)
{
    int i = blockIdx.x * 256 + threadIdx.x;
    if (i >= n8) return;
    const f32x4* xp = reinterpret_cast<const f32x4*>(x + (size_t)i * 8);
    f32x4 v0 = xp[0], v1 = xp[1];
    u16x8 h, l;
#pragma unroll
    for (int j = 0; j < 4; ++j) {
        unsigned short hh = f2bf(v0[j]);
        h[j] = hh; l[j] = f2bf(v0[j] - bf2f(hh));
        hh = f2bf(v1[j]);
        h[4 + j] = hh; l[4 + j] = f2bf(v1[j] - bf2f(hh));
    }
    *reinterpret_cast<u16x8*>(ho + (size_t)i * 8) = h;
    *reinterpret_cast<u16x8*>(lo + (size_t)i * 8) = l;
}

// ---- P0 fused: enc fp32 -> enc_h, enc_l (row-major) + encT (hi transposed) -
__global__ __launch_bounds__(256)
void split_enc_T(const float* __restrict__ enc, unsigned short* __restrict__ eh,
                 unsigned short* __restrict__ el, unsigned short* __restrict__ eT)
{
    __shared__ unsigned short t[64][72];
    const int b = blockIdx.z;
    const int kb = blockIdx.x * 64;   // Tk
    const int db = blockIdx.y * 64;   // D
    const int r = threadIdx.x >> 4;          // 0..15
    const int c0 = (threadIdx.x & 15) * 4;   // 0..60
    const float* ip = enc + ((size_t)b * 2048 + kb) * 1024 + db;
#pragma unroll
    for (int it = 0; it < 4; ++it) {
        int row = it * 16 + r;
        f32x4 v = *reinterpret_cast<const f32x4*>(ip + (size_t)row * 1024 + c0);
        u16x4 h, l;
#pragma unroll
        for (int j = 0; j < 4; ++j) {
            h[j] = f2bf(v[j]); l[j] = f2bf(v[j] - bf2f(h[j]));
        }
        size_t go = ((size_t)b * 2048 + kb + row) * 1024 + db + c0;
        *reinterpret_cast<u16x4*>(eh + go) = h;
        *reinterpret_cast<u16x4*>(el + go) = l;
#pragma unroll
        for (int j = 0; j < 4; ++j) t[c0 + j][row] = h[j];
    }
    __syncthreads();
    const int d = threadIdx.x >> 2;   // 0..63
    const int ch = threadIdx.x & 3;   // k-chunk of 16
    unsigned short* op = eT + ((size_t)b * 1024 + db + d) * 2048 + kb + ch * 16;
    u16x8 w0, w1;
#pragma unroll
    for (int j = 0; j < 8; ++j) { w0[j] = t[d][ch * 16 + j]; w1[j] = t[d][ch * 16 + 8 + j]; }
    *reinterpret_cast<u16x8*>(op) = w0;
    *reinterpret_cast<u16x8*>(op + 8) = w1;
}

// ------- T: bf16 transpose (mid-path only) ----------------------------------
__global__ __launch_bounds__(256)
void transpose_bf16(const unsigned short* __restrict__ in, unsigned short* __restrict__ out)
{
    __shared__ unsigned short t[64][65];
    const int b = blockIdx.z;
    const int kb = blockIdx.x * 64;
    const int db = blockIdx.y * 64;
    const unsigned short* ip = in + ((size_t)b * 2048 + kb) * 1024 + db;
    unsigned short* op = out + ((size_t)b * 1024 + db) * 2048 + kb;
    const int r = threadIdx.x >> 3;
    const int c0 = (threadIdx.x & 7) * 8;
#pragma unroll
    for (int h = 0; h < 2; ++h) {
        u16x8 v = *reinterpret_cast<const u16x8*>(ip + (size_t)(r + h * 32) * 1024 + c0);
#pragma unroll
        for (int j = 0; j < 8; ++j) t[c0 + j][r + h * 32] = v[j];
    }
    __syncthreads();
#pragma unroll
    for (int h = 0; h < 2; ++h) {
        int orow = r + h * 32;
        u16x8 v = *reinterpret_cast<const u16x8*>(&t[orow][c0]);
        *reinterpret_cast<u16x8*>(op + (size_t)orow * 2048 + c0) = v;
    }
}

// ========== wide BT GEMM, 16x16 MFMA, 3-buffer counted-vmcnt pipeline =======
// C = A @ B^T (X3: (Ah+Al)@(Bh+Bl)^T, hi*hi+hi*lo+lo*hi). A [M,K], B [N,K]
// bf16 planes, K%32==0. BM=32*AM (=128), BN=256, BK=32, 8 waves (2x4),
// wave-tile (16*AM)x64, acc[AM][4]. LDS rows 64B, phys chunk=(kc+(row>>1))&3
// (conflict-free, r4-r5 measured). Linear LDS dest (gload_lds) + pre-swizzled
// global src. 3-buffer rotation, counted vmcnt: iter t issues stage(t+2),
// computes buf[t%3], then s_waitcnt vmcnt(LPT) (t+1 done, t+2 in flight) +
// raw s_barrier. LPT = per-thread loads per tile. Prologue stages t0,t1.
// Grid: 1D nwg (nwg%8==0), XCD-swizzled.
// OUTMODE 0: fp32 C. OUTMODE 1: bf16 hi/lo split -> Ch, Cl.
template<int X3, int OUTMODE, int AM>
__global__ __launch_bounds__(512, (X3 ? 1 : 2))
void gemm_wide(const unsigned short* __restrict__ Ah, const unsigned short* __restrict__ Al,
               long long sA,
               const unsigned short* __restrict__ Bh, const unsigned short* __restrict__ Bl,
               long long sB,
               float* __restrict__ C, unsigned short* __restrict__ Ch,
               unsigned short* __restrict__ Cl, long long sC,
               int M, int N, int K)
{
    constexpr int BM  = 32 * AM;
    constexpr int LVL = (BM + 256) * 32;          // u16 elems per plane level
    constexpr int BUF = LVL * (X3 ? 2 : 1);
    constexpr int NI  = (BM + 256) / 128;         // gload16 per thread per plane
    constexpr int LPT = NI * (X3 ? 2 : 1);        // loads per tile per thread
    __shared__ unsigned short smem[3 * BUF];      // x3: 144 KiB, x1: 72 KiB

    const int tid = threadIdx.x, lane = tid & 63, wave = tid >> 6;

    // XCD swizzle + batch decode (m-fastest)
    const int nwg = gridDim.x;
    int orig = (blockIdx.x & 7) * (nwg >> 3) + (blockIdx.x >> 3);
    const int mb = M / BM, nb = N >> 8, bpb = mb * nb;
    const int z = orig / bpb, rem = orig - z * bpb;
    const int bm = (rem % mb) * BM, bn = (rem / mb) << 8;

    Ah += (size_t)z * sA; Bh += (size_t)z * sB;
    if (X3) { Al += (size_t)z * sA; Bl += (size_t)z * sB; }

    // staging geometry: slot c = i*512+tid -> row=c>>2, phys slot s=c&3 holds
    // global chunk g = (s - (r>>1)) & 3 (r = per-matrix row).
    const unsigned short* srcH[NI];
    const unsigned short* srcL[NI];
    int dst[NI];
#pragma unroll
    for (int i = 0; i < NI; ++i) {
        int c = i * 512 + tid, row = c >> 2, s = c & 3;
        int isA = row < BM;
        int r = isA ? row : row - BM;
        int g = (s + 4 - ((r >> 1) & 3)) & 3;
        srcH[i] = (isA ? Ah + (size_t)(bm + r) * K : Bh + (size_t)(bn + r) * K) + g * 8;
        if (X3) srcL[i] = (isA ? Al + (size_t)(bm + r) * K : Bl + (size_t)(bn + r) * K) + g * 8;
        dst[i] = row * 32 + s * 8;
    }

    const int kcL = lane >> 4, fr = lane & 15;
    const int wrow = (wave >> 2) * (16 * AM);
    const int wcol = (wave & 3) * 64;

    f32x4 acc[AM][4] = {};
    const int nt = K >> 5;

    auto STAGE = [&](int bufidx, int kt) {
        unsigned short* bx = smem + bufidx * BUF;
#pragma unroll
        for (int i = 0; i < NI; ++i) {
            gload16(srcH[i] + kt, bx + dst[i]);
            if constexpr (X3) gload16(srcL[i] + kt, bx + LVL + dst[i]);
        }
    };
    auto WAIT_LPT = [&]() {
        if constexpr (LPT == 6) asm volatile("s_waitcnt vmcnt(6)" ::: "memory");
        else                    asm volatile("s_waitcnt vmcnt(3)" ::: "memory");
    };

    // prologue: stage tiles 0,1; wait tile0 done (tile1 stays in flight)
    STAGE(0, 0);
    if (nt > 1) STAGE(1, 32);
    if (nt > 1) WAIT_LPT(); else asm volatile("s_waitcnt vmcnt(0)" ::: "memory");
    __builtin_amdgcn_s_barrier();
    asm volatile("" ::: "memory");

    int cur = 0;
    for (int t = 0; t < nt; ++t) {
        if (t + 2 < nt) {   // issue stage(t+2); overwrites buf computed at t-1 (safe)
            int nb3 = cur + 2; if (nb3 >= 3) nb3 -= 3;
            STAGE(nb3, (t + 2) << 5);
        }
        const unsigned short* base = smem + cur * BUF;
        bf16x8 bh[4], bl[4];
#pragma unroll
        for (int n = 0; n < 4; ++n) {
            int row = wcol + n * 16 + fr;
            int off = (BM + row) * 32 + (((kcL + (row >> 1)) & 3) << 3);
            bh[n] = *reinterpret_cast<const bf16x8*>(base + off);
            if constexpr (X3) bl[n] = *reinterpret_cast<const bf16x8*>(base + LVL + off);
        }
#pragma unroll
        for (int m = 0; m < AM; ++m) {
            int row = wrow + m * 16 + fr;
            int off = row * 32 + (((kcL + (row >> 1)) & 3) << 3);
            bf16x8 ah = *reinterpret_cast<const bf16x8*>(base + off);
            bf16x8 al;
            if constexpr (X3) al = *reinterpret_cast<const bf16x8*>(base + LVL + off);
#pragma unroll
            for (int n = 0; n < 4; ++n) {
                acc[m][n] = __builtin_amdgcn_mfma_f32_16x16x32_bf16(ah, bh[n], acc[m][n], 0, 0, 0);
                if constexpr (X3) {
                    acc[m][n] = __builtin_amdgcn_mfma_f32_16x16x32_bf16(ah, bl[n], acc[m][n], 0, 0, 0);
                    acc[m][n] = __builtin_amdgcn_mfma_f32_16x16x32_bf16(al, bh[n], acc[m][n], 0, 0, 0);
                }
            }
        }
        if (t + 1 < nt) {
            if (t + 2 < nt) WAIT_LPT();   // t+1 landed; t+2 stays in flight
            else asm volatile("s_waitcnt vmcnt(0)" ::: "memory");
            __builtin_amdgcn_s_barrier();
            asm volatile("" ::: "memory");
        }
        ++cur; if (cur >= 3) cur = 0;
    }

    // C/D layout: col = lane&15, row = (lane>>4)*4 + j  [HW-verified]
    if constexpr (OUTMODE == 0) {
        float* Cz = C + (size_t)z * sC;
#pragma unroll
        for (int m = 0; m < AM; ++m)
#pragma unroll
            for (int j = 0; j < 4; ++j) {
                int grow = bm + wrow + m * 16 + (lane >> 4) * 4 + j;
                float* cr = Cz + (size_t)grow * N + bn + wcol + fr;
#pragma unroll
                for (int n = 0; n < 4; ++n) cr[n * 16] = acc[m][n][j];
            }
    } else {
        unsigned short* Chz = Ch + (size_t)z * sC;
        unsigned short* Clz = Cl + (size_t)z * sC;
#pragma unroll
        for (int m = 0; m < AM; ++m)
#pragma unroll
            for (int j = 0; j < 4; ++j) {
                int grow = bm + wrow + m * 16 + (lane >> 4) * 4 + j;
                size_t rb = (size_t)grow * N + bn + wcol + fr;
#pragma unroll
                for (int n = 0; n < 4; ++n) {
                    float v = acc[m][n][j];
                    unsigned short hh = f2bf(v);
                    Chz[rb + n * 16] = hh;
                    Clz[rb + n * 16] = f2bf(v - bf2f(hh));
                }
            }
    }
}

// ---------------- softmax rows (2048 cols) + optional bf16 copy -------------
__global__ __launch_bounds__(256)
void softmax_rows(float* __restrict__ P, unsigned short* __restrict__ albf)
{
    __shared__ float redm[4], reds[4];
    float* p = P + (size_t)blockIdx.x * 2048;
    const int tid = threadIdx.x, lane = tid & 63, wave = tid >> 6;

    f32x4 v0 = *reinterpret_cast<const f32x4*>(p + tid * 4);
    f32x4 v1 = *reinterpret_cast<const f32x4*>(p + 1024 + tid * 4);

    float mx = fmaxf(fmaxf(fmaxf(v0[0], v0[1]), fmaxf(v0[2], v0[3])),
                     fmaxf(fmaxf(v1[0], v1[1]), fmaxf(v1[2], v1[3])));
#pragma unroll
    for (int o = 32; o; o >>= 1) mx = fmaxf(mx, __shfl_xor(mx, o));
    if (lane == 0) redm[wave] = mx;
    __syncthreads();
    mx = fmaxf(fmaxf(redm[0], redm[1]), fmaxf(redm[2], redm[3]));

    float s = 0.f;
#pragma unroll
    for (int j = 0; j < 4; ++j) { v0[j] = __expf(v0[j] - mx); s += v0[j]; }
#pragma unroll
    for (int j = 0; j < 4; ++j) { v1[j] = __expf(v1[j] - mx); s += v1[j]; }
#pragma unroll
    for (int o = 32; o; o >>= 1) s += __shfl_xor(s, o);
    if (lane == 0) reds[wave] = s;
    __syncthreads();
    s = reds[0] + reds[1] + reds[2] + reds[3];

    const float inv = 1.0f / s;
#pragma unroll
    for (int j = 0; j < 4; ++j) { v0[j] *= inv; v1[j] *= inv; }
    *reinterpret_cast<f32x4*>(p + tid * 4) = v0;
    *reinterpret_cast<f32x4*>(p + 1024 + tid * 4) = v1;

    if (albf) {
        unsigned short* ab = albf + (size_t)blockIdx.x * 2048;
        u16x4 h0, h1;
#pragma unroll
        for (int j = 0; j < 4; ++j) { h0[j] = f2bf(v0[j]); h1[j] = f2bf(v1[j]); }
        *reinterpret_cast<u16x4*>(ab + tid * 4) = h0;
        *reinterpret_cast<u16x4*>(ab + 1024 + tid * 4) = h1;
    }
}

// ======================= round-1 fallback kernels ===========================
__device__ inline int tile_byte(int row, int kElem) {
    int chunk = kElem >> 3;
    return row * 128 + ((chunk ^ (row & 7)) << 4) + ((kElem & 7) << 1);
}

__global__ __launch_bounds__(256, 2)
void gemm_bt_x3(const float* __restrict__ A, long long sA,
                const float* __restrict__ Bt, long long sB,
                float* __restrict__ C, long long sC,
                int M, int N, int K)
{
    __shared__ unsigned short Ah[128 * 64], Al[128 * 64];
    __shared__ unsigned short Bh[128 * 64], Bl[128 * 64];

    const int tid = threadIdx.x, lane = tid & 63, wave = tid >> 6;
    const int wr = (wave >> 1) * 64, wc = (wave & 1) * 64;
    const int bm = blockIdx.y * 128, bn = blockIdx.x * 128;
    A += (size_t)blockIdx.z * sA;
    Bt += (size_t)blockIdx.z * sB;
    C += (size_t)blockIdx.z * sC;

    f32x4 acc[4][4] = {};

    for (int kt = 0; kt < K; kt += 64) {
#pragma unroll
        for (int i = 0; i < 8; ++i) {
            int idx = tid + i * 256;
            int row = idx >> 4, f4 = idx & 15;
            f32x4 va = *reinterpret_cast<const f32x4*>(A + (size_t)(bm + row) * K + kt + f4 * 4);
            f32x4 vb = *reinterpret_cast<const f32x4*>(Bt + (size_t)(bn + row) * K + kt + f4 * 4);
            u16x4 ah, al, bh, bl;
#pragma unroll
            for (int j = 0; j < 4; ++j) {
                unsigned short h = f2bf(va[j]);
                ah[j] = h; al[j] = f2bf(va[j] - bf2f(h));
                h = f2bf(vb[j]);
                bh[j] = h; bl[j] = f2bf(vb[j] - bf2f(h));
            }
            int off = tile_byte(row, f4 * 4);
            *reinterpret_cast<u16x4*>((char*)Ah + off) = ah;
            *reinterpret_cast<u16x4*>((char*)Al + off) = al;
            *reinterpret_cast<u16x4*>((char*)Bh + off) = bh;
            *reinterpret_cast<u16x4*>((char*)Bl + off) = bl;
        }
        __syncthreads();
#pragma unroll
        for (int kk = 0; kk < 2; ++kk) {
            bf16x8 a_h[4], a_l[4], b_h[4], b_l[4];
            const int kbase = kk * 32 + (lane >> 4) * 8;
#pragma unroll
            for (int m = 0; m < 4; ++m) {
                int off = tile_byte(wr + m * 16 + (lane & 15), kbase);
                a_h[m] = *reinterpret_cast<const bf16x8*>((char*)Ah + off);
                a_l[m] = *reinterpret_cast<const bf16x8*>((char*)Al + off);
            }
#pragma unroll
            for (int n = 0; n < 4; ++n) {
                int off = tile_byte(wc + n * 16 + (lane & 15), kbase);
                b_h[n] = *reinterpret_cast<const bf16x8*>((char*)Bh + off);
                b_l[n] = *reinterpret_cast<const bf16x8*>((char*)Bl + off);
            }
#pragma unroll
            for (int m = 0; m < 4; ++m)
#pragma unroll
                for (int n = 0; n < 4; ++n) {
                    acc[m][n] = __builtin_amdgcn_mfma_f32_16x16x32_bf16(a_h[m], b_h[n], acc[m][n], 0, 0, 0);
                    acc[m][n] = __builtin_amdgcn_mfma_f32_16x16x32_bf16(a_h[m], b_l[n], acc[m][n], 0, 0, 0);
                    acc[m][n] = __builtin_amdgcn_mfma_f32_16x16x32_bf16(a_l[m], b_h[n], acc[m][n], 0, 0, 0);
                }
        }
        __syncthreads();
    }
#pragma unroll
    for (int m = 0; m < 4; ++m)
#pragma unroll
        for (int j = 0; j < 4; ++j) {
            int grow = bm + wr + m * 16 + (lane >> 4) * 4 + j;
            float* cr = C + (size_t)grow * N + bn + wc + (lane & 15);
#pragma unroll
            for (int n = 0; n < 4; ++n) cr[n * 16] = acc[m][n][j];
        }
}

__global__ __launch_bounds__(256, 2)
void gemm_nn_bf16(const float* __restrict__ A, long long sA,
                  const float* __restrict__ Bn, long long sB,
                  float* __restrict__ C, long long sC,
                  int M, int N, int K)
{
    __shared__ unsigned short As[128 * 64];
    __shared__ unsigned short Bs[64 * 130];

    const int tid = threadIdx.x, lane = tid & 63, wave = tid >> 6;
    const int wr = (wave >> 1) * 64, wc = (wave & 1) * 64;
    const int bm = blockIdx.y * 128, bn = blockIdx.x * 128;
    A += (size_t)blockIdx.z * sA;
    Bn += (size_t)blockIdx.z * sB;
    C += (size_t)blockIdx.z * sC;

    f32x4 acc[4][4] = {};

    for (int kt = 0; kt < K; kt += 64) {
#pragma unroll
        for (int i = 0; i < 8; ++i) {
            int idx = tid + i * 256;
            int row = idx >> 4, f4 = idx & 15;
            f32x4 va = *reinterpret_cast<const f32x4*>(A + (size_t)(bm + row) * K + kt + f4 * 4);
            u16x4 h;
#pragma unroll
            for (int j = 0; j < 4; ++j) h[j] = f2bf(va[j]);
            *reinterpret_cast<u16x4*>((char*)As + tile_byte(row, f4 * 4)) = h;
        }
#pragma unroll
        for (int i = 0; i < 8; ++i) {
            int idx = tid + i * 256;
            int krow = idx >> 5, f4 = idx & 31;
            f32x4 vb = *reinterpret_cast<const f32x4*>(Bn + (size_t)(kt + krow) * N + bn + f4 * 4);
            unsigned int p0 = (unsigned int)f2bf(vb[0]) | ((unsigned int)f2bf(vb[1]) << 16);
            unsigned int p1 = (unsigned int)f2bf(vb[2]) | ((unsigned int)f2bf(vb[3]) << 16);
            unsigned int* bp = reinterpret_cast<unsigned int*>(&Bs[krow * 130 + f4 * 4]);
            bp[0] = p0; bp[1] = p1;
        }
        __syncthreads();
#pragma unroll
        for (int kk = 0; kk < 2; ++kk) {
            bf16x8 a[4], b[4];
            const int kbase = kk * 32 + (lane >> 4) * 8;
#pragma unroll
            for (int m = 0; m < 4; ++m)
                a[m] = *reinterpret_cast<const bf16x8*>((char*)As + tile_byte(wr + m * 16 + (lane & 15), kbase));
#pragma unroll
            for (int n = 0; n < 4; ++n) {
                int col = wc + n * 16 + (lane & 15);
                union { unsigned short u[8]; bf16x8 v; } t;
#pragma unroll
                for (int j = 0; j < 8; ++j) t.u[j] = Bs[(kbase + j) * 130 + col];
                b[n] = t.v;
            }
#pragma unroll
            for (int m = 0; m < 4; ++m)
#pragma unroll
                for (int n = 0; n < 4; ++n)
                    acc[m][n] = __builtin_amdgcn_mfma_f32_16x16x32_bf16(a[m], b[n], acc[m][n], 0, 0, 0);
        }
        __syncthreads();
    }
#pragma unroll
    for (int m = 0; m < 4; ++m)
#pragma unroll
        for (int j = 0; j < 4; ++j) {
            int grow = bm + wr + m * 16 + (lane >> 4) * 4 + j;
            float* cr = C + (size_t)grow * N + bn + wc + (lane & 15);
#pragma unroll
            for (int n = 0; n < 4; ++n) cr[n * 16] = acc[m][n][j];
        }
}

// ============================================================================
extern "C" void kernel_launch(void* const* d_in, const int* in_sizes, int n_in,
                              void* d_out, int out_size, void* d_ws, size_t ws_size,
                              hipStream_t stream)
{
    (void)in_sizes; (void)n_in; (void)out_size;
    const float* dec = (const float*)d_in[0];   // [16,512,1024]
    const float* enc = (const float*)d_in[1];   // [16,2048,1024]
    const float* W   = (const float*)d_in[2];   // [1024,1024]

    float* ctx   = (float*)d_out;                            // [16,512,1024]
    float* align = (float*)d_out + (size_t)16 * 512 * 1024;  // [16,512,2048]

    const size_t MiB = 1048576ULL;
    const size_t NEED_FUSED = 224 * MiB;
    const size_t NEED_FAST  = 160 * MiB;

    if (ws_size >= NEED_FAST) {
        const bool fused = (ws_size >= NEED_FUSED);
        unsigned short* enc_h   = (unsigned short*)d_ws;             // 64 MiB
        unsigned short* enc_l   = enc_h + 33554432ULL;               // 64 MiB
        unsigned short* encT    = fused ? (enc_l + 33554432ULL)
                                        : enc_l;                     // alias after K2
        unsigned short* align_b = fused ? (encT + 33554432ULL)
                                        : (enc_l + 33554432ULL);     // 32 MiB
        unsigned short* dproj_h = (unsigned short*)d_out;            // ctx region (dead)
        unsigned short* dproj_l = dproj_h + 8388608ULL;
        unsigned short* dec_h   = (unsigned short*)align;            // align region (dead)
        unsigned short* dec_l   = dec_h + 8388608ULL;
        unsigned short* W_h     = dec_l + 8388608ULL;
        unsigned short* W_l     = W_h + 1048576ULL;

        // P0: splits (+ fused transpose when encT has its own region)
        if (fused)
            split_enc_T<<<dim3(32, 16, 16), 256, 0, stream>>>(enc, enc_h, enc_l, encT);
        else
            split_bf16<<<16384, 256, 0, stream>>>(enc, enc_h, enc_l, 4194304);
        split_bf16<<<4096, 256, 0, stream>>>(dec, dec_h, dec_l, 1048576);
        split_bf16<<<512, 256, 0, stream>>>(W, W_h, W_l, 131072);

        // K1: dproj = dec @ W^T  (M=8192, N=1024, K=1024), 128x256, 3-buf
        gemm_wide<1, 1, 4><<<256, 512, 0, stream>>>(
            dec_h, dec_l, 0, W_h, W_l, 0,
            nullptr, dproj_h, dproj_l, 0, 8192, 1024, 1024);

        // K2: score = dproj @ enc^T per batch (M=512, N=2048, K=1024), 128x256, 3-buf
        gemm_wide<1, 0, 4><<<512, 512, 0, stream>>>(
            dproj_h, dproj_l, 512LL * 1024, enc_h, enc_l, 2048LL * 1024,
            align, nullptr, nullptr, 512LL * 2048, 512, 2048, 1024);

        // mid path: transpose enc_h into enc_l region (dead after K2)
        if (!fused)
            transpose_bf16<<<dim3(32, 16, 16), 256, 0, stream>>>(enc_h, encT);

        // K3: softmax + bf16 copy
        softmax_rows<<<8192, 256, 0, stream>>>(align, align_b);

        // K4: ctx = align_b @ encT^T per batch (M=512, N=1024, K=2048), 128x256, 3-buf
        gemm_wide<0, 0, 4><<<256, 512, 0, stream>>>(
            align_b, nullptr, 512LL * 2048, encT, nullptr, 1024LL * 2048,
            ctx, nullptr, nullptr, 512LL * 1024, 512, 1024, 2048);
    } else {
        // round-1 fallback (needs 32 MiB ws)
        float* dproj = (float*)d_ws;
        gemm_bt_x3<<<dim3(8, 64, 1), 256, 0, stream>>>(
            dec, 0, W, 0, dproj, 0, 8192, 1024, 1024);
        gemm_bt_x3<<<dim3(16, 4, 16), 256, 0, stream>>>(
            dproj, 512LL * 1024, enc, 2048LL * 1024, align, 512LL * 2048, 512, 2048, 1024);
        softmax_rows<<<8192, 256, 0, stream>>>(align, nullptr);
        gemm_nn_bf16<<<dim3(8, 4, 16), 256, 0, stream>>>(
            align, 512LL * 2048, enc, 2048LL * 1024, ctx, 512LL * 1024, 512, 1024, 2048);
    }
}

// Round 10
// 266.228 us; speedup vs baseline: 1.2256x; 1.1815x over previous
//
#include <hip/hip_runtime.h>
#include <hip/hip_bf16.h>

// LuongAttention: B=16, Tq=512, Tk=2048, D=1024 (fp32 in/out)
// Fast path (ws >= 160 MiB), all-fp16 planes:
//   P0: split_enc_T: enc -> enc_h (fp16) + encT (fp16, transposed); dec h/l; W h
//   K1: dproj_h/l = split(dec @ W_h^T)   gemm_wide<2,1,4>  (128x256, 2-ph dbuf)
//   K2: score = (dproj_h+l) @ enc_h^T    gemm_wide<2,0,8>  (256x256, 2-ph dbuf)
//   K3: softmax in place + fp16 copy (align_h)
//   K4: ctx = align_h @ encT^T           gemm_wide<1,0,4>  (128x256, 2-ph dbuf)
// fp16-x2 decomposition: A split into fp16 hi+lo (captures ~22 bits), B single
// fp16. Dropped a*b_l term ~ 4.5e-3 std on score (alignment err ~0.01 << 0.104
// threshold). vs bf16-x3: 2/3 the MFMAs, 3/4 the LDS planes, enc_l eliminated.
// GEMM schedule = round-5 proven 2-phase dbuf (phase-split/32x32/3-buf all
// regressed, r6-r8). wa_bias cancels in softmax -> skipped.
// Fallback (<160 MiB): round-1 bf16 kernels (need 32 MiB ws).

typedef float f32x4 __attribute__((ext_vector_type(4)));
typedef _Float16 f16x8 __attribute__((ext_vector_type(8)));
typedef __bf16 bf16x8 __attribute__((ext_vector_type(8)));
typedef unsigned short u16x4 __attribute__((ext_vector_type(4)));
typedef unsigned short u16x8 __attribute__((ext_vector_type(8)));

__device__ inline unsigned short h_bits(_Float16 h) {
    union { _Float16 h; unsigned short u; } v; v.h = h; return v.u;
}
// returns hi fp16 bits in [15:0], lo fp16 bits in [31:16]
__device__ inline unsigned int split_f16(float x) {
    _Float16 h = (_Float16)x;
    _Float16 l = (_Float16)(x - (float)h);
    return (unsigned int)h_bits(h) | ((unsigned int)h_bits(l) << 16);
}

__device__ inline void gload16(const void* g, const void* l) {
    __builtin_amdgcn_global_load_lds(
        (const __attribute__((address_space(1))) unsigned int*)g,
        (__attribute__((address_space(3))) unsigned int*)l, 16, 0, 0);
}

// ---------------- P0: fp32 -> fp16 hi(/lo) split (elementwise) --------------
__global__ __launch_bounds__(256)
void splitf16(const float* __restrict__ x, unsigned short* __restrict__ ho,
              unsigned short* __restrict__ lo, int n8)
{
    int i = blockIdx.x * 256 + threadIdx.x;
    if (i >= n8) return;
    const f32x4* xp = reinterpret_cast<const f32x4*>(x + (size_t)i * 8);
    f32x4 v0 = xp[0], v1 = xp[1];
    u16x8 h, l;
#pragma unroll
    for (int j = 0; j < 4; ++j) {
        unsigned int p0 = split_f16(v0[j]);
        unsigned int p1 = split_f16(v1[j]);
        h[j] = (unsigned short)p0;      l[j] = (unsigned short)(p0 >> 16);
        h[4 + j] = (unsigned short)p1;  l[4 + j] = (unsigned short)(p1 >> 16);
    }
    *reinterpret_cast<u16x8*>(ho + (size_t)i * 8) = h;
    if (lo) *reinterpret_cast<u16x8*>(lo + (size_t)i * 8) = l;
}

// ---- P0 fused: enc fp32 -> enc_h (fp16 row-major) + encT (fp16 transposed) -
// enc [16][2048][1024]; encT [16][1024][2048]. 64x64 tiles.
__global__ __launch_bounds__(256)
void split_enc_T(const float* __restrict__ enc, unsigned short* __restrict__ eh,
                 unsigned short* __restrict__ eT)
{
    __shared__ unsigned short t[64][68];   // [d][k], 68 stride breaks bank alias
    const int b = blockIdx.z;
    const int kb = blockIdx.x * 64;   // Tk
    const int db = blockIdx.y * 64;   // D
    const int r = threadIdx.x >> 4;          // 0..15
    const int c0 = (threadIdx.x & 15) * 4;   // 0..60
    const float* ip = enc + ((size_t)b * 2048 + kb) * 1024 + db;
#pragma unroll
    for (int it = 0; it < 4; ++it) {
        int row = it * 16 + r;
        f32x4 v = *reinterpret_cast<const f32x4*>(ip + (size_t)row * 1024 + c0);
        u16x4 h;
#pragma unroll
        for (int j = 0; j < 4; ++j) h[j] = h_bits((_Float16)v[j]);
        *reinterpret_cast<u16x4*>(eh + ((size_t)b * 2048 + kb + row) * 1024 + db + c0) = h;
#pragma unroll
        for (int j = 0; j < 4; ++j) t[c0 + j][row] = h[j];
    }
    __syncthreads();
    const int d = threadIdx.x >> 2;   // 0..63 (D within tile)
    const int ch = threadIdx.x & 3;   // k-chunk of 16
    unsigned short* op = eT + ((size_t)b * 1024 + db + d) * 2048 + kb + ch * 16;
    u16x8 w0, w1;
#pragma unroll
    for (int j = 0; j < 8; ++j) { w0[j] = t[d][ch * 16 + j]; w1[j] = t[d][ch * 16 + 8 + j]; }
    *reinterpret_cast<u16x8*>(op) = w0;
    *reinterpret_cast<u16x8*>(op + 8) = w1;
}

// ========== wide BT GEMM, fp16, 16x16x32 MFMA, 2-phase dbuf (r5 schedule) ===
// C = (Ah[+Al]) @ Bh^T. A planes [M,K], B plane [N,K] fp16, K%32==0.
// BM=32*AM, BN=256, BK=32, 8 waves (2x4), wave-tile (16*AM)x64, acc[AM][4].
// Row-plane list: rp in [0,BM) = Ah rows, [BM,BM*APL) = Al rows,
// [RA, RA+256) = Bh rows. LDS rows 64B, phys chunk = (kc+(rp>>1))&3
// (conflict-free, measured r4/r5). Linear LDS dest (gload_lds) + pre-swizzled
// global src. 2-phase: stage(next buf) issued BEFORE compute(cur), one
// __syncthreads per K-tile. Grid: 1D nwg (nwg%8==0), XCD-swizzled, m-fastest.
// OUTMODE 0: fp32 C. OUTMODE 1: fp16 hi/lo split -> Ch, Cl.
// C/D layout [HW-verified]: col = lane&15, row = (lane>>4)*4 + j.
template<int APL, int OUTMODE, int AM>
__global__ __launch_bounds__(512, 2)
void gemm_wide(const unsigned short* __restrict__ Ah, const unsigned short* __restrict__ Al,
               long long sA,
               const unsigned short* __restrict__ Bh, long long sB,
               float* __restrict__ C, unsigned short* __restrict__ Ch,
               unsigned short* __restrict__ Cl, long long sC,
               int M, int N, int K)
{
    constexpr int BM  = 32 * AM;
    constexpr int RA  = BM * APL;                 // A row-planes
    constexpr int TOT = RA + 256;                 // + B row-planes
    constexpr int NI  = TOT / 128;                // gload16 per thread per tile
    constexpr int BUF = TOT * 32;                 // u16 elems per buffer
    __shared__ unsigned short smem[2 * BUF];

    const int tid = threadIdx.x, lane = tid & 63, wave = tid >> 6;

    // XCD swizzle + batch decode (m-fastest)
    const int nwg = gridDim.x;
    int orig = (blockIdx.x & 7) * (nwg >> 3) + (blockIdx.x >> 3);
    const int mb = M / BM, nb = N >> 8, bpb = mb * nb;
    const int z = orig / bpb, rem = orig - z * bpb;
    const int bm = (rem % mb) * BM, bn = (rem / mb) << 8;

    Ah += (size_t)z * sA; Bh += (size_t)z * sB;
    if (APL == 2) Al += (size_t)z * sA;

    // staging geometry: slot c = i*512+tid -> rp = c>>2, phys slot s = c&3
    // holds global chunk g = (s - (rp>>1)) & 3.
    const unsigned short* src[NI];
    int dst[NI];
#pragma unroll
    for (int i = 0; i < NI; ++i) {
        int c = i * 512 + tid, rp = c >> 2, s = c & 3;
        int g = (s + 4 - ((rp >> 1) & 3)) & 3;
        const unsigned short* bp;
        if (rp < BM)                    bp = Ah + (size_t)(bm + rp) * K;
        else if (APL == 2 && rp < RA)   bp = Al + (size_t)(bm + rp - BM) * K;
        else                            bp = Bh + (size_t)(bn + rp - RA) * K;
        src[i] = bp + g * 8;
        dst[i] = rp * 32 + s * 8;
    }

    const int kcL = lane >> 4, fr = lane & 15;
    const int wrow = (wave >> 2) * (16 * AM);
    const int wcol = (wave & 3) * 64;

    f32x4 acc[AM][4] = {};
    const int nt = K >> 5;
    int cur = 0;

    {   // prologue: stage K-tile 0 into buf 0
#pragma unroll
        for (int i = 0; i < NI; ++i) gload16(src[i], smem + dst[i]);
    }
    __syncthreads();

    for (int t = 0; t < nt; ++t) {
        if (t + 1 < nt) {   // issue next-tile stage BEFORE compute (2-phase)
            const int kt = (t + 1) << 5;
            unsigned short* bx = smem + (cur ^ 1) * BUF;
#pragma unroll
            for (int i = 0; i < NI; ++i) gload16(src[i] + kt, bx + dst[i]);
        }
        const unsigned short* base = smem + cur * BUF;
        f16x8 bhf[4];
#pragma unroll
        for (int n = 0; n < 4; ++n) {
            int rp = RA + wcol + n * 16 + fr;
            bhf[n] = *reinterpret_cast<const f16x8*>(base + rp * 32 + (((kcL + (rp >> 1)) & 3) << 3));
        }
#pragma unroll
        for (int m = 0; m < AM; ++m) {
            int ra = wrow + m * 16 + fr;
            f16x8 ah = *reinterpret_cast<const f16x8*>(base + ra * 32 + (((kcL + (ra >> 1)) & 3) << 3));
            f16x8 al;
            if (APL == 2) {
                int rp = BM + ra;
                al = *reinterpret_cast<const f16x8*>(base + rp * 32 + (((kcL + (rp >> 1)) & 3) << 3));
            }
#pragma unroll
            for (int n = 0; n < 4; ++n) {
                acc[m][n] = __builtin_amdgcn_mfma_f32_16x16x32_f16(ah, bhf[n], acc[m][n], 0, 0, 0);
                if (APL == 2)
                    acc[m][n] = __builtin_amdgcn_mfma_f32_16x16x32_f16(al, bhf[n], acc[m][n], 0, 0, 0);
            }
        }
        __syncthreads();   // drains vmcnt: next buf staged; reads of cur done
        cur ^= 1;
    }

    // C/D layout: col = lane&15, row = (lane>>4)*4 + j  [HW-verified]
    if constexpr (OUTMODE == 0) {
        float* Cz = C + (size_t)z * sC;
#pragma unroll
        for (int m = 0; m < AM; ++m)
#pragma unroll
            for (int j = 0; j < 4; ++j) {
                int grow = bm + wrow + m * 16 + (lane >> 4) * 4 + j;
                float* cr = Cz + (size_t)grow * N + bn + wcol + fr;
#pragma unroll
                for (int n = 0; n < 4; ++n) cr[n * 16] = acc[m][n][j];
            }
    } else {
        unsigned short* Chz = Ch + (size_t)z * sC;
        unsigned short* Clz = Cl + (size_t)z * sC;
#pragma unroll
        for (int m = 0; m < AM; ++m)
#pragma unroll
            for (int j = 0; j < 4; ++j) {
                int grow = bm + wrow + m * 16 + (lane >> 4) * 4 + j;
                size_t rb = (size_t)grow * N + bn + wcol + fr;
#pragma unroll
                for (int n = 0; n < 4; ++n) {
                    unsigned int p = split_f16(acc[m][n][j]);
                    Chz[rb + n * 16] = (unsigned short)p;
                    Clz[rb + n * 16] = (unsigned short)(p >> 16);
                }
            }
    }
}

// ---------------- softmax rows (2048 cols) + optional fp16 copy -------------
__global__ __launch_bounds__(256)
void softmax_rows(float* __restrict__ P, unsigned short* __restrict__ alh)
{
    __shared__ float redm[4], reds[4];
    float* p = P + (size_t)blockIdx.x * 2048;
    const int tid = threadIdx.x, lane = tid & 63, wave = tid >> 6;

    f32x4 v0 = *reinterpret_cast<const f32x4*>(p + tid * 4);
    f32x4 v1 = *reinterpret_cast<const f32x4*>(p + 1024 + tid * 4);

    float mx = fmaxf(fmaxf(fmaxf(v0[0], v0[1]), fmaxf(v0[2], v0[3])),
                     fmaxf(fmaxf(v1[0], v1[1]), fmaxf(v1[2], v1[3])));
#pragma unroll
    for (int o = 32; o; o >>= 1) mx = fmaxf(mx, __shfl_xor(mx, o));
    if (lane == 0) redm[wave] = mx;
    __syncthreads();
    mx = fmaxf(fmaxf(redm[0], redm[1]), fmaxf(redm[2], redm[3]));

    float s = 0.f;
#pragma unroll
    for (int j = 0; j < 4; ++j) { v0[j] = __expf(v0[j] - mx); s += v0[j]; }
#pragma unroll
    for (int j = 0; j < 4; ++j) { v1[j] = __expf(v1[j] - mx); s += v1[j]; }
#pragma unroll
    for (int o = 32; o; o >>= 1) s += __shfl_xor(s, o);
    if (lane == 0) reds[wave] = s;
    __syncthreads();
    s = reds[0] + reds[1] + reds[2] + reds[3];

    const float inv = 1.0f / s;
#pragma unroll
    for (int j = 0; j < 4; ++j) { v0[j] *= inv; v1[j] *= inv; }
    *reinterpret_cast<f32x4*>(p + tid * 4) = v0;
    *reinterpret_cast<f32x4*>(p + 1024 + tid * 4) = v1;

    if (alh) {
        unsigned short* ab = alh + (size_t)blockIdx.x * 2048;
        u16x4 h0, h1;
#pragma unroll
        for (int j = 0; j < 4; ++j) {
            h0[j] = h_bits((_Float16)v0[j]);
            h1[j] = h_bits((_Float16)v1[j]);
        }
        *reinterpret_cast<u16x4*>(ab + tid * 4) = h0;
        *reinterpret_cast<u16x4*>(ab + 1024 + tid * 4) = h1;
    }
}

// ======================= round-1 fallback kernels (bf16) ====================
__device__ inline unsigned short f2bf(float f) {
    union { float f; unsigned int u; } v; v.f = f;
    unsigned int r = v.u + 0x7fffu + ((v.u >> 16) & 1u);
    return (unsigned short)(r >> 16);
}
__device__ inline float bf2f(unsigned short h) {
    union { unsigned int u; float f; } v; v.u = ((unsigned int)h) << 16; return v.f;
}
__device__ inline int tile_byte(int row, int kElem) {
    int chunk = kElem >> 3;
    return row * 128 + ((chunk ^ (row & 7)) << 4) + ((kElem & 7) << 1);
}

__global__ __launch_bounds__(256, 2)
void gemm_bt_x3(const float* __restrict__ A, long long sA,
                const float* __restrict__ Bt, long long sB,
                float* __restrict__ C, long long sC,
                int M, int N, int K)
{
    __shared__ unsigned short Ah[128 * 64], Al[128 * 64];
    __shared__ unsigned short Bh[128 * 64], Bl[128 * 64];

    const int tid = threadIdx.x, lane = tid & 63, wave = tid >> 6;
    const int wr = (wave >> 1) * 64, wc = (wave & 1) * 64;
    const int bm = blockIdx.y * 128, bn = blockIdx.x * 128;
    A += (size_t)blockIdx.z * sA;
    Bt += (size_t)blockIdx.z * sB;
    C += (size_t)blockIdx.z * sC;

    f32x4 acc[4][4] = {};

    for (int kt = 0; kt < K; kt += 64) {
#pragma unroll
        for (int i = 0; i < 8; ++i) {
            int idx = tid + i * 256;
            int row = idx >> 4, f4 = idx & 15;
            f32x4 va = *reinterpret_cast<const f32x4*>(A + (size_t)(bm + row) * K + kt + f4 * 4);
            f32x4 vb = *reinterpret_cast<const f32x4*>(Bt + (size_t)(bn + row) * K + kt + f4 * 4);
            u16x4 ah, al, bh, bl;
#pragma unroll
            for (int j = 0; j < 4; ++j) {
                unsigned short h = f2bf(va[j]);
                ah[j] = h; al[j] = f2bf(va[j] - bf2f(h));
                h = f2bf(vb[j]);
                bh[j] = h; bl[j] = f2bf(vb[j] - bf2f(h));
            }
            int off = tile_byte(row, f4 * 4);
            *reinterpret_cast<u16x4*>((char*)Ah + off) = ah;
            *reinterpret_cast<u16x4*>((char*)Al + off) = al;
            *reinterpret_cast<u16x4*>((char*)Bh + off) = bh;
            *reinterpret_cast<u16x4*>((char*)Bl + off) = bl;
        }
        __syncthreads();
#pragma unroll
        for (int kk = 0; kk < 2; ++kk) {
            bf16x8 a_h[4], a_l[4], b_h[4], b_l[4];
            const int kbase = kk * 32 + (lane >> 4) * 8;
#pragma unroll
            for (int m = 0; m < 4; ++m) {
                int off = tile_byte(wr + m * 16 + (lane & 15), kbase);
                a_h[m] = *reinterpret_cast<const bf16x8*>((char*)Ah + off);
                a_l[m] = *reinterpret_cast<const bf16x8*>((char*)Al + off);
            }
#pragma unroll
            for (int n = 0; n < 4; ++n) {
                int off = tile_byte(wc + n * 16 + (lane & 15), kbase);
                b_h[n] = *reinterpret_cast<const bf16x8*>((char*)Bh + off);
                b_l[n] = *reinterpret_cast<const bf16x8*>((char*)Bl + off);
            }
#pragma unroll
            for (int m = 0; m < 4; ++m)
#pragma unroll
                for (int n = 0; n < 4; ++n) {
                    acc[m][n] = __builtin_amdgcn_mfma_f32_16x16x32_bf16(a_h[m], b_h[n], acc[m][n], 0, 0, 0);
                    acc[m][n] = __builtin_amdgcn_mfma_f32_16x16x32_bf16(a_h[m], b_l[n], acc[m][n], 0, 0, 0);
                    acc[m][n] = __builtin_amdgcn_mfma_f32_16x16x32_bf16(a_l[m], b_h[n], acc[m][n], 0, 0, 0);
                }
        }
        __syncthreads();
    }
#pragma unroll
    for (int m = 0; m < 4; ++m)
#pragma unroll
        for (int j = 0; j < 4; ++j) {
            int grow = bm + wr + m * 16 + (lane >> 4) * 4 + j;
            float* cr = C + (size_t)grow * N + bn + wc + (lane & 15);
#pragma unroll
            for (int n = 0; n < 4; ++n) cr[n * 16] = acc[m][n][j];
        }
}

__global__ __launch_bounds__(256, 2)
void gemm_nn_bf16(const float* __restrict__ A, long long sA,
                  const float* __restrict__ Bn, long long sB,
                  float* __restrict__ C, long long sC,
                  int M, int N, int K)
{
    __shared__ unsigned short As[128 * 64];
    __shared__ unsigned short Bs[64 * 130];

    const int tid = threadIdx.x, lane = tid & 63, wave = tid >> 6;
    const int wr = (wave >> 1) * 64, wc = (wave & 1) * 64;
    const int bm = blockIdx.y * 128, bn = blockIdx.x * 128;
    A += (size_t)blockIdx.z * sA;
    Bn += (size_t)blockIdx.z * sB;
    C += (size_t)blockIdx.z * sC;

    f32x4 acc[4][4] = {};

    for (int kt = 0; kt < K; kt += 64) {
#pragma unroll
        for (int i = 0; i < 8; ++i) {
            int idx = tid + i * 256;
            int row = idx >> 4, f4 = idx & 15;
            f32x4 va = *reinterpret_cast<const f32x4*>(A + (size_t)(bm + row) * K + kt + f4 * 4);
            u16x4 h;
#pragma unroll
            for (int j = 0; j < 4; ++j) h[j] = f2bf(va[j]);
            *reinterpret_cast<u16x4*>((char*)As + tile_byte(row, f4 * 4)) = h;
        }
#pragma unroll
        for (int i = 0; i < 8; ++i) {
            int idx = tid + i * 256;
            int krow = idx >> 5, f4 = idx & 31;
            f32x4 vb = *reinterpret_cast<const f32x4*>(Bn + (size_t)(kt + krow) * N + bn + f4 * 4);
            unsigned int p0 = (unsigned int)f2bf(vb[0]) | ((unsigned int)f2bf(vb[1]) << 16);
            unsigned int p1 = (unsigned int)f2bf(vb[2]) | ((unsigned int)f2bf(vb[3]) << 16);
            unsigned int* bp = reinterpret_cast<unsigned int*>(&Bs[krow * 130 + f4 * 4]);
            bp[0] = p0; bp[1] = p1;
        }
        __syncthreads();
#pragma unroll
        for (int kk = 0; kk < 2; ++kk) {
            bf16x8 a[4], b[4];
            const int kbase = kk * 32 + (lane >> 4) * 8;
#pragma unroll
            for (int m = 0; m < 4; ++m)
                a[m] = *reinterpret_cast<const bf16x8*>((char*)As + tile_byte(wr + m * 16 + (lane & 15), kbase));
#pragma unroll
            for (int n = 0; n < 4; ++n) {
                int col = wc + n * 16 + (lane & 15);
                union { unsigned short u[8]; bf16x8 v; } t;
#pragma unroll
                for (int j = 0; j < 8; ++j) t.u[j] = Bs[(kbase + j) * 130 + col];
                b[n] = t.v;
            }
#pragma unroll
            for (int m = 0; m < 4; ++m)
#pragma unroll
                for (int n = 0; n < 4; ++n)
                    acc[m][n] = __builtin_amdgcn_mfma_f32_16x16x32_bf16(a[m], b[n], acc[m][n], 0, 0, 0);
        }
        __syncthreads();
    }
#pragma unroll
    for (int m = 0; m < 4; ++m)
#pragma unroll
        for (int j = 0; j < 4; ++j) {
            int grow = bm + wr + m * 16 + (lane >> 4) * 4 + j;
            float* cr = C + (size_t)grow * N + bn + wc + (lane & 15);
#pragma unroll
            for (int n = 0; n < 4; ++n) cr[n * 16] = acc[m][n][j];
        }
}

// ============================================================================
extern "C" void kernel_launch(void* const* d_in, const int* in_sizes, int n_in,
                              void* d_out, int out_size, void* d_ws, size_t ws_size,
                              hipStream_t stream)
{
    (void)in_sizes; (void)n_in; (void)out_size;
    const float* dec = (const float*)d_in[0];   // [16,512,1024]
    const float* enc = (const float*)d_in[1];   // [16,2048,1024]
    const float* W   = (const float*)d_in[2];   // [1024,1024]

    float* ctx   = (float*)d_out;                            // [16,512,1024]
    float* align = (float*)d_out + (size_t)16 * 512 * 1024;  // [16,512,2048]

    const size_t NEED_FAST = 160ULL * 1048576ULL;  // enc_h + encT + align_h

    if (ws_size >= NEED_FAST) {
        unsigned short* enc_h   = (unsigned short*)d_ws;             // 64 MiB
        unsigned short* encT    = enc_h + 33554432ULL;               // 64 MiB
        unsigned short* align_h = encT + 33554432ULL;                // 32 MiB
        unsigned short* dproj_h = (unsigned short*)d_out;            // ctx region (dead until K4)
        unsigned short* dproj_l = dproj_h + 8388608ULL;
        unsigned short* dec_h   = (unsigned short*)align;            // align region (dead until K2)
        unsigned short* dec_l   = dec_h + 8388608ULL;
        unsigned short* W_h     = dec_l + 8388608ULL;

        // P0: enc -> enc_h + encT (fused transpose); dec h/l; W h only
        split_enc_T<<<dim3(32, 16, 16), 256, 0, stream>>>(enc, enc_h, encT);
        splitf16<<<4096, 256, 0, stream>>>(dec, dec_h, dec_l, 1048576);
        splitf16<<<512, 256, 0, stream>>>(W, W_h, nullptr, 131072);

        // K1: dproj = dec @ W_h^T  (M=8192, N=1024, K=1024) -> fp16 h/l planes
        gemm_wide<2, 1, 4><<<256, 512, 0, stream>>>(
            dec_h, dec_l, 0, W_h, 0,
            nullptr, dproj_h, dproj_l, 0, 8192, 1024, 1024);

        // K2: score = dproj @ enc_h^T per batch (M=512, N=2048, K=1024) -> align
        gemm_wide<2, 0, 8><<<256, 512, 0, stream>>>(
            dproj_h, dproj_l, 512LL * 1024, enc_h, 2048LL * 1024,
            align, nullptr, nullptr, 512LL * 2048, 512, 2048, 1024);

        // K3: softmax + fp16 copy
        softmax_rows<<<8192, 256, 0, stream>>>(align, align_h);

        // K4: ctx = align_h @ encT^T per batch (M=512, N=1024, K=2048)
        gemm_wide<1, 0, 4><<<256, 512, 0, stream>>>(
            align_h, nullptr, 512LL * 2048, encT, 1024LL * 2048,
            ctx, nullptr, nullptr, 512LL * 1024, 512, 1024, 2048);
    } else {
        // round-1 fallback (needs 32 MiB ws)
        float* dproj = (float*)d_ws;
        gemm_bt_x3<<<dim3(8, 64, 1), 256, 0, stream>>>(
            dec, 0, W, 0, dproj, 0, 8192, 1024, 1024);
        gemm_bt_x3<<<dim3(16, 4, 16), 256, 0, stream>>>(
            dproj, 512LL * 1024, enc, 2048LL * 1024, align, 512LL * 2048, 512, 2048, 1024);
        softmax_rows<<<8192, 256, 0, stream>>>(align, nullptr);
        gemm_nn_bf16<<<dim3(8, 4, 16), 256, 0, stream>>>(
            align, 512LL * 2048, enc, 2048LL * 1024, ctx, 512LL * 1024, 512, 1024, 2048);
    }
}